// Round 2
// baseline (9108.990 us; speedup 1.0000x reference)
//
#include <hip/hip_runtime.h>
#include <cstddef>

// ---------- types ----------
typedef _Float16 f16x8 __attribute__((ext_vector_type(8)));
typedef _Float16 f16x4 __attribute__((ext_vector_type(4)));
typedef short    s16x8 __attribute__((ext_vector_type(8)));
typedef short    s16x4 __attribute__((ext_vector_type(4)));
typedef float    f32x4 __attribute__((ext_vector_type(4)));

#define MFMA_F16(a, b, c) __builtin_amdgcn_mfma_f32_16x16x32_f16((a), (b), (c), 0, 0, 0)

constexpr int GB = 512, GT = 256, GF = 64;
constexpr int GH1 = 256, GH2 = 128, GH3 = 64;

#if __has_builtin(__builtin_amdgcn_rcpf)
__device__ __forceinline__ float fast_rcp(float x) { return __builtin_amdgcn_rcpf(x); }
#else
__device__ __forceinline__ float fast_rcp(float x) { return 1.f / x; }
#endif

__device__ __forceinline__ f16x8 ld8(const short* p) {
  return __builtin_bit_cast(f16x8, *(const s16x8*)p);
}
__device__ __forceinline__ f16x4 ld4(const short* p) {
  return __builtin_bit_cast(f16x4, *(const s16x4*)p);
}

// LDS-only barrier: global prefetches/stores stay in flight across it.
__device__ __forceinline__ void barrier_nodrain() {
  asm volatile("s_waitcnt lgkmcnt(0)" ::: "memory");
  __builtin_amdgcn_s_barrier();
  asm volatile("" ::: "memory");
}

// ---------- chunk flag protocol (agent scope) ----------
__device__ __forceinline__ void stage_wait(int* f, int target, int tid) {
  if (tid == 0) {
    while (__hip_atomic_load(f, __ATOMIC_ACQUIRE, __HIP_MEMORY_SCOPE_AGENT) < target)
      __builtin_amdgcn_s_sleep(2);
  }
  __syncthreads();
  __threadfence();  // invalidate stale lines (ring slots are reused)
}
__device__ __forceinline__ void stage_publish(int* f, int val, int tid) {
  asm volatile("s_waitcnt vmcnt(0)" ::: "memory");  // per-wave: all stores done
  __syncthreads();
  if (tid == 0)
    __hip_atomic_store(f, val, __ATOMIC_RELEASE, __HIP_MEMORY_SCOPE_AGENT);
}

// ---------- fp32 -> fp16 casts + flag zeroing, one launch ----------
struct CastDesc { const float* src; short* dst; int n; };
struct CastArgs { CastDesc d[7]; int* flags; };

__global__ void cast_many(CastArgs a) {
  const int tid = blockIdx.x * blockDim.x + threadIdx.x;
  const int stride = gridDim.x * blockDim.x;
  if (blockIdx.x == 0 && threadIdx.x < 128) a.flags[threadIdx.x] = 0;
#pragma unroll
  for (int j = 0; j < 7; j++) {
    const float* __restrict__ s = a.d[j].src;
    short* __restrict__ o = a.d[j].dst;
    const int n = a.d[j].n;
    for (int i = tid; i < n; i += stride)
      o[i] = __builtin_bit_cast(short, (_Float16)s[i]);
  }
}

// ---------- stage g1: x @ Wih1^T + b_ih1 -> xg1 ring (tile-major) ----------
template <int KK, int NO, int JT>
__device__ __forceinline__ void g1_run(const short* __restrict__ A,
                                       const short* __restrict__ W,
                                       const float* __restrict__ bias,
                                       short* __restrict__ ring,
                                       int* Fout, int* Fbp,
                                       int bt, int C, int NB, int tid) {
  constexpr int KC = KK / 32;
  const int lane = tid & 63, wid = tid >> 6;
  const int p = lane & 15, q = lane >> 4;
  const int j0 = wid * 16 * JT;

  f16x8 wb[JT][KC];
  float bc[JT];
#pragma unroll
  for (int jt = 0; jt < JT; jt++) {
    const int col = j0 + jt * 16 + p;
    bc[jt] = bias[col];
#pragma unroll
    for (int kc = 0; kc < KC; kc++)
      wb[jt][kc] = ld8(W + (size_t)col * KK + kc * 32 + q * 8);
  }
  const short* arow = A + (size_t)(bt * 16 + p) * GT * KK + q * 8;
  const int NC = GT / C;

  f16x8 ab0[KC], ab1[KC];
#pragma unroll
  for (int kc = 0; kc < KC; kc++) ab0[kc] = ld8(arow + kc * 32);  // t = 0

  auto body = [&](int t, short* slot, int ti, f16x8 (&ac)[KC], f16x8 (&an)[KC]) {
    // prefetch t+1 (overrun at t=255 lands in the weights region: harmless)
#pragma unroll
    for (int kc = 0; kc < KC; kc++)
      an[kc] = ld8(arow + (size_t)(t + 1) * KK + kc * 32);
    f32x4 acc[JT];
#pragma unroll
    for (int jt = 0; jt < JT; jt++)
      acc[jt] = f32x4{bc[jt], bc[jt], bc[jt], bc[jt]};
#pragma unroll
    for (int kc = 0; kc < KC; kc++)
#pragma unroll
      for (int jt = 0; jt < JT; jt++)
        acc[jt] = MFMA_F16(ac[kc], wb[jt][kc], acc[jt]);
    short* ob = slot + (size_t)ti * NO * 16;
#pragma unroll
    for (int jt = 0; jt < JT; jt++) {  // C/D: col = lane&15, row = q*4+r
      const int col = j0 + jt * 16 + p;
      s16x4 v;
#pragma unroll
      for (int r = 0; r < 4; r++)
        v[r] = __builtin_bit_cast(short, (_Float16)acc[jt][r]);
      *(s16x4*)&ob[col * 16 + q * 4] = v;
    }
  };

  for (int c = 0; c < NC; ++c) {
    if (c >= NB) stage_wait(Fbp + bt, c + 1 - NB, tid);  // ring backpressure
    short* slot = ring + ((size_t)(c % NB) * 32 + bt) * ((size_t)C * NO * 16);
#pragma unroll 1
    for (int ti = 0; ti < C; ti += 2) {  // C even: static double-buffer parity
      body(c * C + ti, slot, ti, ab0, ab1);
      body(c * C + ti + 1, slot, ti + 1, ab1, ab0);
    }
    stage_publish(Fout + bt, c + 1, tid);
  }
}

// ---------- rec stage: sequential GRU over T, chunked, flag-chained ----------
// XG=true : input gates come precomputed from the xg ring (r1).
// XG=false: input projection inline; Wih register-resident (r2, r3).
// Whh r,z register-resident; n-gate: KREG k-frags in regs, rest in LDS.
template <int H, int HIN, int JT, int KREG, bool SEQ, bool XG>
__device__ __forceinline__ void rec_run(const short* __restrict__ xin,  // XG ? ring : [B,T,HIN] fp16
                                        const short* __restrict__ Wih,  // !XG
                                        const short* __restrict__ Whh,
                                        const float* __restrict__ bih,  // !XG
                                        const float* __restrict__ bhh,
                                        short* __restrict__ hout,       // SEQ
                                        float* __restrict__ hfin,       // !SEQ: [B,H] fp32
                                        int* Fin, int* Fout,
                                        int bt, int C, int NB, int tid, short* smem) {
  constexpr int KS = H / 32;
  constexpr int KSI = HIN / 32;
  constexpr int KLDS = KS - KREG;
  constexpr int HP = H + 8;
  constexpr int WNP = KLDS * 32 + 8;
  constexpr int NO = 3 * H;

  short* wn = smem;                                // [H][WNP] if KLDS>0
  short* hb = smem + (KLDS > 0 ? H * WNP : 0);     // [2][16][HP]

  const int lane = tid & 63, wid = tid >> 6;
  const int p = lane & 15, q = lane >> 4;
  const int b0 = bt * 16;
  const int j0 = wid * 16 * JT;

  if constexpr (KLDS > 0) {  // stage n-gate k-tail of Whh into LDS (once)
    constexpr int KV = KLDS * 4;
    for (int i = tid; i < H * KV; i += 256) {
      const int row = i / KV, kc = i - row * KV;
      *(s16x8*)&wn[row * WNP + kc * 8] =
          *(const s16x8*)&Whh[(size_t)(2 * H + row) * H + KREG * 32 + kc * 8];
    }
  }
  for (int i = tid; i < 2 * 16 * HP; i += 256) hb[i] = 0;

  // register-resident weights
  f16x8 wrz[JT][2][KS];
  f16x8 wnr[JT][KREG > 0 ? KREG : 1];
  f16x8 wih[XG ? 1 : JT][3][XG ? 1 : KSI];
#pragma unroll
  for (int jt = 0; jt < JT; jt++) {
    const int col = j0 + jt * 16 + p;
#pragma unroll
    for (int g = 0; g < 2; g++)
#pragma unroll
      for (int k = 0; k < KS; k++)
        wrz[jt][g][k] = ld8(Whh + (size_t)(g * H + col) * H + k * 32 + q * 8);
#pragma unroll
    for (int k = 0; k < KREG; k++)
      wnr[jt][k] = ld8(Whh + (size_t)(2 * H + col) * H + k * 32 + q * 8);
  }
  if constexpr (!XG) {
#pragma unroll
    for (int jt = 0; jt < JT; jt++) {
      const int col = j0 + jt * 16 + p;
#pragma unroll
      for (int g = 0; g < 3; g++)
#pragma unroll
        for (int k = 0; k < KSI; k++)
          wih[jt][g][k] = ld8(Wih + (size_t)(g * H + col) * HIN + k * 32 + q * 8);
    }
  }

  float br[JT], bz[JT], bn_h[JT], bn_x[XG ? 1 : JT];
  int wrow[JT], loff[XG ? JT : 1][3];
#pragma unroll
  for (int jt = 0; jt < JT; jt++) {
    const int col = j0 + jt * 16 + p;
    wrow[jt] = col;
    bn_h[jt] = bhh[2 * H + col];
    if constexpr (XG) {
      br[jt] = bhh[col];
      bz[jt] = bhh[H + col];
#pragma unroll
      for (int g = 0; g < 3; g++) loff[jt][g] = (g * H + col) * 16 + q * 4;
    } else {
      br[jt] = bih[col] + bhh[col];
      bz[jt] = bih[H + col] + bhh[H + col];
      bn_x[jt] = bih[2 * H + col];
    }
  }

  float hprev[JT][4];
#pragma unroll
  for (int jt = 0; jt < JT; jt++)
#pragma unroll
    for (int r = 0; r < 4; r++) hprev[jt][r] = 0.f;

  const short* xrow = nullptr;
  if constexpr (!XG) xrow = xin + (size_t)(b0 + p) * GT * HIN + q * 8;

  f16x4 xb4[2][XG ? JT : 1][3];
  f16x8 xb8[2][XG ? 1 : KSI];

  __syncthreads();

  const int NC = GT / C;
  for (int c = 0; c < NC; ++c) {
    stage_wait(Fin + bt, c + 1, tid);
    const short* xchunk = nullptr;
    if constexpr (XG)
      xchunk = xin + ((size_t)(c % NB) * 32 + bt) * ((size_t)C * NO * 16);
    // prime 2 steps of input prefetch (within flagged chunk only)
#pragma unroll
    for (int u = 0; u < 2; u++) {
      if constexpr (XG) {
#pragma unroll
        for (int jt = 0; jt < JT; jt++)
#pragma unroll
          for (int g = 0; g < 3; g++)
            xb4[u][jt][g] = ld4(xchunk + (size_t)u * NO * 16 + loff[jt][g]);
      } else {
#pragma unroll
        for (int k = 0; k < KSI; k++)
          xb8[u][k] = ld8(xrow + (size_t)(c * C + u) * HIN + k * 32);
      }
    }

#pragma unroll 1
    for (int s = 0; s < C; ++s) {
      const int t = c * C + s;
      const int u = s & 1;            // C even: chunk starts at buffer 0
      short* hbc = hb + u * 16 * HP;
      short* hbn = hb + (u ^ 1) * 16 * HP;

      f32x4 ar[JT], az[JT], an[JT], axn[XG ? 1 : JT];
#pragma unroll
      for (int jt = 0; jt < JT; jt++) {
        if constexpr (XG) {
#pragma unroll
          for (int r = 0; r < 4; r++) {
            ar[jt][r] = (float)xb4[u][jt][0][r];
            az[jt][r] = (float)xb4[u][jt][1][r];
          }
        } else {
          ar[jt] = f32x4{0.f, 0.f, 0.f, 0.f};
          az[jt] = f32x4{0.f, 0.f, 0.f, 0.f};
          axn[jt] = f32x4{0.f, 0.f, 0.f, 0.f};
        }
        an[jt] = f32x4{0.f, 0.f, 0.f, 0.f};
      }

      // recurrence: k outer, h fragment shared across jt
#pragma unroll
      for (int k = 0; k < KS; k++) {
        const f16x8 ahk = ld8(&hbc[p * HP + k * 32 + q * 8]);
#pragma unroll
        for (int jt = 0; jt < JT; jt++) {
          ar[jt] = MFMA_F16(ahk, wrz[jt][0][k], ar[jt]);
          az[jt] = MFMA_F16(ahk, wrz[jt][1][k], az[jt]);
          if (k < KREG) {
            an[jt] = MFMA_F16(ahk, wnr[jt][k < KREG ? k : 0], an[jt]);
          } else {
            const f16x8 wnk = ld8(&wn[wrow[jt] * WNP + (k - KREG) * 32 + q * 8]);
            an[jt] = MFMA_F16(ahk, wnk, an[jt]);
          }
        }
      }
      // inline input projection (registers only)
      if constexpr (!XG) {
#pragma unroll
        for (int k = 0; k < KSI; k++)
#pragma unroll
          for (int jt = 0; jt < JT; jt++) {
            ar[jt] = MFMA_F16(xb8[u][k], wih[jt][0][k], ar[jt]);
            az[jt] = MFMA_F16(xb8[u][k], wih[jt][1][k], az[jt]);
            axn[jt] = MFMA_F16(xb8[u][k], wih[jt][2][k], axn[jt]);
          }
      }

      // epilogue: C/D layout col = lane&15, row = q*4+r
#pragma unroll
      for (int jt = 0; jt < JT; jt++) {
        const int col = j0 + jt * 16 + p;
#pragma unroll
        for (int r = 0; r < 4; r++) {
          const int bm = q * 4 + r;
          const float rpre = ar[jt][r] + br[jt];
          const float zpre = az[jt][r] + bz[jt];
          const float rg = fast_rcp(1.f + __expf(-rpre));
          const float zg = fast_rcp(1.f + __expf(-zpre));
          float xnv;
          if constexpr (XG) xnv = (float)xb4[u][jt][2][r];
          else              xnv = axn[jt][r] + bn_x[jt];
          const float narg = xnv + rg * (an[jt][r] + bn_h[jt]);
          const float e2 = __expf(2.f * narg);
          const float ng = 1.f - 2.f * fast_rcp(e2 + 1.f);  // tanh
          const float hnew = (1.f - zg) * ng + zg * hprev[jt][r];
          hprev[jt][r] = hnew;
          const _Float16 hf = (_Float16)hnew;
          hbn[bm * HP + col] = __builtin_bit_cast(short, hf);
          if constexpr (SEQ)
            hout[((size_t)(b0 + bm) * GT + t) * H + col] = __builtin_bit_cast(short, hf);
          else if (t == GT - 1)
            hfin[(size_t)(b0 + bm) * H + col] = hnew;
        }
      }
      // refill xb[u] for step s+2 (stay inside the flagged chunk)
      if (s + 2 < C) {
        if constexpr (XG) {
#pragma unroll
          for (int jt = 0; jt < JT; jt++)
#pragma unroll
            for (int g = 0; g < 3; g++)
              xb4[u][jt][g] = ld4(xchunk + (size_t)(s + 2) * NO * 16 + loff[jt][g]);
        } else {
#pragma unroll
          for (int k = 0; k < KSI; k++)
            xb8[u][k] = ld8(xrow + (size_t)(t + 2) * HIN + k * 32);
        }
      }
      barrier_nodrain();
    }
    if (Fout) stage_publish(Fout + bt, c + 1, tid);
  }
}

// ---------- the persistent 4-stage pipeline ----------
struct PipeArgs {
  const short* xh;
  const short* wih1; const short* whh1; const float* bih1; const float* bhh1;
  const short* wih2; const short* whh2; const float* bih2; const float* bhh2;
  const short* wih3; const short* whh3; const float* bih3; const float* bhh3;
  short* xg1; short* h1; short* h2; float* hstate;
  int* F1; int* F2; int* F3;
  int C, NB;
};

__global__ __launch_bounds__(256, 1)
void gru_pipe(PipeArgs a) {
  extern __shared__ __align__(16) short smem[];
  const int stage = blockIdx.x >> 5, bt = blockIdx.x & 31;
  const int tid = threadIdx.x;
  if (stage == 0) {
    g1_run<GF, 3 * GH1, 12>(a.xh, a.wih1, a.bih1, a.xg1, a.F1, a.F2, bt, a.C, a.NB, tid);
  } else if (stage == 1) {
    rec_run<GH1, GF, 4, 4, true, true>(a.xg1, nullptr, a.whh1, nullptr, a.bhh1,
                                       a.h1, nullptr, a.F1, a.F2, bt, a.C, a.NB, tid, smem);
  } else if (stage == 2) {
    rec_run<GH2, GH1, 2, 4, true, false>(a.h1, a.wih2, a.whh2, a.bih2, a.bhh2,
                                         a.h2, nullptr, a.F2, a.F3, bt, a.C, a.NB, tid, smem);
  } else {
    rec_run<GH3, GH2, 1, 2, false, false>(a.h2, a.wih3, a.whh3, a.bih3, a.bhh3,
                                          nullptr, a.hstate, a.F3, nullptr, bt, a.C, a.NB, tid, smem);
  }
}

// ---------- dense head ----------
__global__ void dense_kernel(const float* __restrict__ hl, const float* __restrict__ Wd,
                             const float* __restrict__ bd, float* __restrict__ out) {
  const int b = blockIdx.x * 64 + threadIdx.x;
  float a = bd[0];
#pragma unroll
  for (int k = 0; k < 64; k++) a = fmaf(hl[b * 64 + k], Wd[k], a);
  out[b] = a;
}

// ---------- host ----------
extern "C" void kernel_launch(void* const* d_in, const int* in_sizes, int n_in,
                              void* d_out, int out_size, void* d_ws, size_t ws_size,
                              hipStream_t stream) {
  constexpr int B = GB, T = GT, F = GF;
  constexpr int H1 = GH1, H2 = GH2, H3 = GH3;
  constexpr int M = B * T;

  const float* x     = (const float*)d_in[0];
  const float* W_ih1 = (const float*)d_in[1];
  const float* W_hh1 = (const float*)d_in[2];
  const float* b_ih1 = (const float*)d_in[3];
  const float* b_hh1 = (const float*)d_in[4];
  const float* W_ih2 = (const float*)d_in[5];
  const float* W_hh2 = (const float*)d_in[6];
  const float* b_ih2 = (const float*)d_in[7];
  const float* b_hh2 = (const float*)d_in[8];
  const float* W_ih3 = (const float*)d_in[9];
  const float* W_hh3 = (const float*)d_in[10];
  const float* b_ih3 = (const float*)d_in[11];
  const float* b_hh3 = (const float*)d_in[12];
  const float* W_d   = (const float*)d_in[13];
  const float* b_d   = (const float*)d_in[14];
  float* out = (float*)d_out;

  char* ws = (char*)d_ws;
  size_t off = 0;
  auto alloc = [&](size_t bytes) -> char* {
    char* pp = ws + off;
    off = (off + bytes + 255) & ~(size_t)255;
    return pp;
  };

  const int nx    = M * F;
  const int nwih1 = 3 * H1 * F,  nwhh1 = 3 * H1 * H1;
  const int nwih2 = 3 * H2 * H1, nwhh2 = 3 * H2 * H2;
  const int nwih3 = 3 * H3 * H2, nwhh3 = 3 * H3 * H3;

  short* xh     = (short*)alloc((size_t)nx * 2);       // x prefetch overrun lands in wih1: safe
  short* wih1   = (short*)alloc((size_t)nwih1 * 2);
  short* whh1   = (short*)alloc((size_t)nwhh1 * 2);
  short* wih2   = (short*)alloc((size_t)nwih2 * 2);
  short* whh2   = (short*)alloc((size_t)nwhh2 * 2);
  short* wih3   = (short*)alloc((size_t)nwih3 * 2);
  short* whh3   = (short*)alloc((size_t)nwhh3 * 2);
  short* h1     = (short*)alloc((size_t)M * H1 * 2);
  short* h2     = (short*)alloc((size_t)M * H2 * 2);
  float* hstate = (float*)alloc((size_t)B * H3 * 4);
  int*   flags  = (int*)alloc(128 * sizeof(int));
  short* xg1    = (short*)(ws + off);
  (void)n_in; (void)in_sizes; (void)out_size;

  // chunk length / ring depth from available workspace
  const size_t perC = (size_t)32 * (3 * H1) * 16 * 2;  // ring bytes per timestep
  int C = 4;
  if      (off + 2 * 16 * perC <= ws_size) C = 16;
  else if (off + 2 *  8 * perC <= ws_size) C = 8;
  const size_t slot = (size_t)C * perC;
  int NB = (ws_size > off) ? (int)((ws_size - off) / slot) : 2;
  NB = NB < 2 ? 2 : (NB > 6 ? 6 : NB);

  CastArgs ca;
  ca.d[0] = {x, xh, nx};
  ca.d[1] = {W_ih1, wih1, nwih1};
  ca.d[2] = {W_hh1, whh1, nwhh1};
  ca.d[3] = {W_ih2, wih2, nwih2};
  ca.d[4] = {W_hh2, whh2, nwhh2};
  ca.d[5] = {W_ih3, wih3, nwih3};
  ca.d[6] = {W_hh3, whh3, nwhh3};
  ca.flags = flags;
  cast_many<<<1024, 256, 0, stream>>>(ca);

  // LDS: r1 stage needs wn[256][136] + hb[2][16][264] fp16 = 86528 B (max over stages)
  constexpr int SMEM = 256 * 136 * 2 + 2 * 16 * (H1 + 8) * 2;
  (void)hipFuncSetAttribute((const void*)gru_pipe, hipFuncAttributeMaxDynamicSharedMemorySize, SMEM);

  PipeArgs pa;
  pa.xh = xh;
  pa.wih1 = wih1; pa.whh1 = whh1; pa.bih1 = b_ih1; pa.bhh1 = b_hh1;
  pa.wih2 = wih2; pa.whh2 = whh2; pa.bih2 = b_ih2; pa.bhh2 = b_hh2;
  pa.wih3 = wih3; pa.whh3 = whh3; pa.bih3 = b_ih3; pa.bhh3 = b_hh3;
  pa.xg1 = xg1; pa.h1 = h1; pa.h2 = h2; pa.hstate = hstate;
  pa.F1 = flags; pa.F2 = flags + 32; pa.F3 = flags + 64;
  pa.C = C; pa.NB = NB;

  gru_pipe<<<128, 256, SMEM, stream>>>(pa);

  dense_kernel<<<B / 64, 64, 0, stream>>>(hstate, W_d, b_d, out);
}